// Round 2
// baseline (129.880 us; speedup 1.0000x reference)
//
#include <hip/hip_runtime.h>
#include <math.h>

#define BLOCK 256
#define PPT 4            // owned points per thread -> 1024 points per block
#define NCHUNK 16        // opposing dimension split into 16 chunks of 512
#define FBLOCKS 128      // finalize blocks

// ---- order-preserving float <-> uint key (works for negatives) ----
__device__ __forceinline__ unsigned f2key(float f) {
    unsigned b = __float_as_uint(f);
    return b ^ ((b & 0x80000000u) ? 0xFFFFFFFFu : 0x80000000u);
}
__device__ __forceinline__ float key2f(unsigned k) {
    unsigned b = k ^ ((k & 0x80000000u) ? 0x80000000u : 0xFFFFFFFFu);
    return __uint_as_float(b);
}

// Phase 0: pre-scale both point sets into one float4 array:
//   pre[i] = (-2x, -2y, -2z, x^2+y^2+z^2)
// layout: [0..n1) from a1, [n1..n1+n2) from a2
__global__ __launch_bounds__(256) void prescale_kernel(
    const float* __restrict__ a1, const float* __restrict__ a2,
    float4* __restrict__ pre, int n1, int n2)
{
    int i = blockIdx.x * 256 + threadIdx.x;
    const float* p;
    if (i < n1)            p = a1 + 3 * (size_t)i;
    else if (i < n1 + n2)  p = a2 + 3 * (size_t)(i - n1);
    else return;
    float x = p[0], y = p[1], z = p[2];
    pre[i] = make_float4(-2.0f * x, -2.0f * y, -2.0f * z,
                         __builtin_fmaf(x, x, __builtin_fmaf(y, y, z * z)));
}

// Phase 1: for each owned point, min over a chunk of opposing points of
// (b^2 - 2 a.b). b-chunk values are wave-uniform -> read straight from the
// pre-scaled global array (uniform/broadcast loads; no LDS pipe contention).
__global__ __launch_bounds__(BLOCK) void chamfer_min_kernel(
    const float4* __restrict__ pre, int Bb, int N, int M,
    unsigned* __restrict__ wsmin)
{
    const int dir = blockIdx.z;
    const int nA = dir ? M : N;
    const int nB = dir ? N : M;
    const float4* preA = pre + (dir ? (size_t)Bb * N : 0);   // owned
    const float4* preB = pre + (dir ? 0 : (size_t)Bb * N);   // scanned
    unsigned* wmin = wsmin + (dir ? (size_t)Bb * N : 0);

    const int clen = nB / NCHUNK;                    // 512
    const int a_start = blockIdx.x * (BLOCK * PPT);  // flat index into [Bb*nA)
    const int batch   = a_start / nA;
    const float4* cb = preB + (size_t)batch * nB + (size_t)blockIdx.y * clen;

    // Owned points: coalesced float4 loads; undo the -2 scale (once per 512 j's)
    float ax[PPT], ay[PPT], az[PPT], mn[PPT];
#pragma unroll
    for (int k = 0; k < PPT; ++k) {
        float4 a = preA[a_start + threadIdx.x + k * BLOCK];
        ax[k] = -0.5f * a.x;
        ay[k] = -0.5f * a.y;
        az[k] = -0.5f * a.z;
        mn[k] = __builtin_inff();
    }

    // Inner scan, 2 opposing points per step:
    // per (2j, k): 6 fma + 1 min3  (LLVM folds fmin(fmin) -> v_min3_f32)
#pragma unroll 4
    for (int j = 0; j < clen; j += 2) {
        float4 b0 = cb[j];
        float4 b1 = cb[j + 1];
#pragma unroll
        for (int k = 0; k < PPT; ++k) {
            float u0 = __builtin_fmaf(b0.x, ax[k],
                       __builtin_fmaf(b0.y, ay[k],
                       __builtin_fmaf(b0.z, az[k], b0.w)));
            float u1 = __builtin_fmaf(b1.x, ax[k],
                       __builtin_fmaf(b1.y, ay[k],
                       __builtin_fmaf(b1.z, az[k], b1.w)));
            mn[k] = fminf(mn[k], fminf(u0, u1));
        }
    }

    // Combine partial mins across chunks
#pragma unroll
    for (int k = 0; k < PPT; ++k) {
        atomicMin(&wmin[a_start + threadIdx.x + k * BLOCK], f2key(mn[k]));
    }
}

// Phase 2: multi-block weighted sum; one fp32 atomicAdd per block.
// result = sum_{i<BN} (|a_i|^2 + min_i)/BN + sum_{i in [BN,BN+BM)} (...)/BM
__global__ __launch_bounds__(256) void chamfer_finalize_kernel(
    const float4* __restrict__ pre, const unsigned* __restrict__ wsmin,
    int BN, int BM, float* __restrict__ out)
{
    const int total = BN + BM;
    const float wA = 1.0f / (float)BN;
    const float wB = 1.0f / (float)BM;

    float s = 0.0f;
    for (int i = blockIdx.x * 256 + threadIdx.x; i < total; i += 256 * FBLOCKS) {
        float w = (i < BN) ? wA : wB;
        s += w * (pre[i].w + key2f(wsmin[i]));
    }

    // wave64 shuffle reduce
#pragma unroll
    for (int off = 32; off > 0; off >>= 1)
        s += __shfl_down(s, off, 64);

    __shared__ float wsum[4];
    int lane = threadIdx.x & 63, wv = threadIdx.x >> 6;
    if (lane == 0) wsum[wv] = s;
    __syncthreads();
    if (threadIdx.x == 0)
        atomicAdd(out, wsum[0] + wsum[1] + wsum[2] + wsum[3]);
}

extern "C" void kernel_launch(void* const* d_in, const int* in_sizes, int n_in,
                              void* d_out, int out_size, void* d_ws, size_t ws_size,
                              hipStream_t stream)
{
    const float* arr1 = (const float*)d_in[0];
    const float* arr2 = (const float*)d_in[1];
    float* out = (float*)d_out;

    const int Bb = 4;
    const int N = in_sizes[0] / (Bb * 3);   // 8192
    const int M = in_sizes[1] / (Bb * 3);   // 8192
    const int BN = Bb * N, BM = Bb * M;

    // ws layout: [keys: (BN+BM) x u32][prescaled: (BN+BM) x float4]
    unsigned* wsmin = (unsigned*)d_ws;
    const size_t nkeys = (size_t)BN + BM;
    float4* pre = (float4*)((char*)d_ws + nkeys * sizeof(unsigned));

    // Init min-keys to max, out to 0
    hipMemsetAsync(wsmin, 0xFF, nkeys * sizeof(unsigned), stream);
    hipMemsetAsync(out, 0, sizeof(float), stream);

    prescale_kernel<<<(unsigned)((nkeys + 255) / 256), 256, 0, stream>>>(
        arr1, arr2, pre, BN, BM);

    dim3 grid(BN / (BLOCK * PPT), NCHUNK, 2);   // (32, 16, 2)
    chamfer_min_kernel<<<grid, BLOCK, 0, stream>>>(pre, Bb, N, M, wsmin);

    chamfer_finalize_kernel<<<FBLOCKS, 256, 0, stream>>>(pre, wsmin, BN, BM, out);
}

// Round 3
// 108.175 us; speedup vs baseline: 1.2007x; 1.2007x over previous
//
#include <hip/hip_runtime.h>
#include <math.h>

#define BLOCK 256
#define PPT 4            // owned points per thread -> 1024 points per block
#define FBLOCKS 256      // finalize blocks

// Phase 1: for each owned point p (register-resident), scan a chunk of the
// opposing set (staged in LDS, pre-scaled to (-2x,-2y,-2z,|b|^2)) and record
// the chunk-partial min of (b^2 - 2 a.b) via a PLAIN store (no init, no
// atomics):  part[dir][chunk][point].  a^2 added in finalize.
__global__ __launch_bounds__(BLOCK) void chamfer_min_kernel(
    const float* __restrict__ arr1, const float* __restrict__ arr2,
    int Bb, int N, int M, int nchunk,
    float* __restrict__ part, float* __restrict__ out)
{
    const int dir = blockIdx.z;
    const int nA = dir ? M : N;
    const int nB = dir ? N : M;
    const float* Aptr = dir ? arr2 : arr1;   // owned points
    const float* Bptr = dir ? arr1 : arr2;   // scanned points
    const int BN = Bb * N;
    const int nOwn = Bb * nA;
    float* pbase = part + (dir ? (size_t)nchunk * BN : 0);

    // Zero the output accumulator exactly once (finalize runs after this
    // dispatch completes, so ordering + visibility are guaranteed).
    if (blockIdx.x == 0 && blockIdx.y == 0 && blockIdx.z == 0 && threadIdx.x == 0)
        out[0] = 0.0f;

    const int clen = nB / nchunk;
    const int a_start = blockIdx.x * (BLOCK * PPT);  // flat index into [nOwn)
    const int batch   = a_start / nA;                // 1024 | 8192 -> exact

    extern __shared__ float4 sb[];                   // clen entries

    // Stage chunk of scanned points, pre-scaled: (-2x, -2y, -2z, |b|^2)
    {
        const float* bbase = Bptr + ((size_t)batch * nB + (size_t)blockIdx.y * clen) * 3;
        for (int i = threadIdx.x; i < clen; i += BLOCK) {
            float x = bbase[i * 3 + 0];
            float y = bbase[i * 3 + 1];
            float z = bbase[i * 3 + 2];
            sb[i] = make_float4(-2.0f * x, -2.0f * y, -2.0f * z,
                                __builtin_fmaf(x, x, __builtin_fmaf(y, y, z * z)));
        }
    }
    __syncthreads();

    // Owned points in registers (raw coords)
    float ax[PPT], ay[PPT], az[PPT], mn[PPT];
    const float* abase = Aptr + (size_t)a_start * 3;
#pragma unroll
    for (int k = 0; k < PPT; ++k) {
        int idx = threadIdx.x + k * BLOCK;
        ax[k] = abase[idx * 3 + 0];
        ay[k] = abase[idx * 3 + 1];
        az[k] = abase[idx * 3 + 2];
        mn[k] = __builtin_inff();
    }

    // Inner scan, 2 opposing points per step:
    // per (2j, k): 6 fma + 1 min3 -> 3.5 VALU per pair-eval.
    // sb[j] reads are wave-uniform -> LDS broadcast, conflict-free.
#pragma unroll 4
    for (int j = 0; j < clen; j += 2) {
        float4 b0 = sb[j];
        float4 b1 = sb[j + 1];
#pragma unroll
        for (int k = 0; k < PPT; ++k) {
            float u0 = __builtin_fmaf(b0.x, ax[k],
                       __builtin_fmaf(b0.y, ay[k],
                       __builtin_fmaf(b0.z, az[k], b0.w)));
            float u1 = __builtin_fmaf(b1.x, ax[k],
                       __builtin_fmaf(b1.y, ay[k],
                       __builtin_fmaf(b1.z, az[k], b1.w)));
            mn[k] = fminf(mn[k], fminf(u0, u1));
        }
    }

    // Plain (coalesced) store of this chunk's partial min
    float* prow = pbase + (size_t)blockIdx.y * nOwn + a_start;
#pragma unroll
    for (int k = 0; k < PPT; ++k)
        prow[threadIdx.x + k * BLOCK] = mn[k];
}

// Phase 2: per point, min over nchunk partials + |a|^2; weighted sum;
// one fp32 atomicAdd per block.
__global__ __launch_bounds__(256) void chamfer_finalize_kernel(
    const float* __restrict__ arr1, const float* __restrict__ arr2,
    const float* __restrict__ part, int BN, int BM, int nchunk,
    float* __restrict__ out)
{
    const int total = BN + BM;
    const float wA = 1.0f / (float)BN;
    const float wB = 1.0f / (float)BM;

    float s = 0.0f;
    for (int i = blockIdx.x * 256 + threadIdx.x; i < total; i += 256 * FBLOCKS) {
        const float* arr;
        const float* pb;
        int idx, stride;
        float w;
        if (i < BN) { arr = arr1; pb = part;                        idx = i;      stride = BN; w = wA; }
        else        { arr = arr2; pb = part + (size_t)nchunk * BN;  idx = i - BN; stride = BM; w = wB; }

        float mn = pb[idx];
        for (int c = 1; c < nchunk; ++c)
            mn = fminf(mn, pb[(size_t)c * stride + idx]);

        float x = arr[idx * 3 + 0], y = arr[idx * 3 + 1], z = arr[idx * 3 + 2];
        s += w * (mn + __builtin_fmaf(x, x, __builtin_fmaf(y, y, z * z)));
    }

    // wave64 shuffle reduce, then cross-wave via LDS
#pragma unroll
    for (int off = 32; off > 0; off >>= 1)
        s += __shfl_down(s, off, 64);

    __shared__ float wsum[4];
    int lane = threadIdx.x & 63, wv = threadIdx.x >> 6;
    if (lane == 0) wsum[wv] = s;
    __syncthreads();
    if (threadIdx.x == 0)
        atomicAdd(out, wsum[0] + wsum[1] + wsum[2] + wsum[3]);
}

extern "C" void kernel_launch(void* const* d_in, const int* in_sizes, int n_in,
                              void* d_out, int out_size, void* d_ws, size_t ws_size,
                              hipStream_t stream)
{
    const float* arr1 = (const float*)d_in[0];
    const float* arr2 = (const float*)d_in[1];
    float* out = (float*)d_out;

    const int Bb = 4;
    const int N = in_sizes[0] / (Bb * 3);   // 8192
    const int M = in_sizes[1] / (Bb * 3);   // 8192
    const int BN = Bb * N, BM = Bb * M;

    // Pick nchunk for occupancy (2048 blocks at 32) but stay inside ws_size.
    int nchunk = 32;
    while (nchunk > 4 && (size_t)(BN + BM) * (size_t)nchunk * sizeof(float) > ws_size)
        nchunk >>= 1;

    float* part = (float*)d_ws;   // [2][nchunk][32768] partial mins

    const int clen = M / nchunk;  // == N / nchunk (both 8192)
    dim3 grid(BN / (BLOCK * PPT), nchunk, 2);   // (32, nchunk, 2)
    chamfer_min_kernel<<<grid, BLOCK, clen * sizeof(float4), stream>>>(
        arr1, arr2, Bb, N, M, nchunk, part, out);

    chamfer_finalize_kernel<<<FBLOCKS, 256, 0, stream>>>(
        arr1, arr2, part, BN, BM, nchunk, out);
}

// Round 4
// 108.032 us; speedup vs baseline: 1.2022x; 1.0013x over previous
//
#include <hip/hip_runtime.h>
#include <math.h>

#define BLOCK 256
#define PPT 8            // owned points per thread -> 2048 points per block
#define NCHUNK 32        // opposing dimension split into chunks of 256
#define FBLOCKS 256      // finalize blocks

// Phase 1: for each owned point p (register-resident), scan a chunk of the
// opposing set (staged in LDS, pre-scaled to (-2x,-2y,-2z,|b|^2)) and record
// the chunk-partial min of (b^2 - 2 a.b) via a PLAIN store (no init, no
// atomics):  part[dir][chunk][point].  a^2 added in finalize.
//
// Cycle budget per staged point j per wave: 1 ds_read_b128 (~12 LDS-cyc/CU)
// vs PPT*3.5 = 28 VALU instr = 14 CU-cyc -> VALU-bound (PPT=4 was LDS-bound).
__global__ __launch_bounds__(BLOCK) void chamfer_min_kernel(
    const float* __restrict__ arr1, const float* __restrict__ arr2,
    int Bb, int N, int M, int nchunk,
    float* __restrict__ part, float* __restrict__ out)
{
    const int dir = blockIdx.z;
    const int nA = dir ? M : N;
    const int nB = dir ? N : M;
    const float* Aptr = dir ? arr2 : arr1;   // owned points
    const float* Bptr = dir ? arr1 : arr2;   // scanned points
    const int BN = Bb * N;
    const int nOwn = Bb * nA;
    float* pbase = part + (dir ? (size_t)nchunk * BN : 0);

    // Zero the output accumulator exactly once (finalize is a later dispatch,
    // so ordering + visibility are guaranteed).
    if (blockIdx.x == 0 && blockIdx.y == 0 && blockIdx.z == 0 && threadIdx.x == 0)
        out[0] = 0.0f;

    const int clen = nB / nchunk;
    const int a_start = blockIdx.x * (BLOCK * PPT);  // flat index into [nOwn)
    const int batch   = a_start / nA;                // 2048 | 8192 -> exact

    extern __shared__ float4 sb[];                   // clen entries

    // Stage chunk of scanned points, pre-scaled: (-2x, -2y, -2z, |b|^2)
    {
        const float* bbase = Bptr + ((size_t)batch * nB + (size_t)blockIdx.y * clen) * 3;
        for (int i = threadIdx.x; i < clen; i += BLOCK) {
            float x = bbase[i * 3 + 0];
            float y = bbase[i * 3 + 1];
            float z = bbase[i * 3 + 2];
            sb[i] = make_float4(-2.0f * x, -2.0f * y, -2.0f * z,
                                __builtin_fmaf(x, x, __builtin_fmaf(y, y, z * z)));
        }
    }
    __syncthreads();

    // Owned points in registers (raw coords)
    float ax[PPT], ay[PPT], az[PPT], mn[PPT];
    const float* abase = Aptr + (size_t)a_start * 3;
#pragma unroll
    for (int k = 0; k < PPT; ++k) {
        int idx = threadIdx.x + k * BLOCK;
        ax[k] = abase[idx * 3 + 0];
        ay[k] = abase[idx * 3 + 1];
        az[k] = abase[idx * 3 + 2];
        mn[k] = __builtin_inff();
    }

    // Inner scan, 2 opposing points per step:
    // per (2j, k): 6 fma + 1 min3 -> 3.5 VALU per pair-eval.
    // sb[j] reads are wave-uniform -> LDS broadcast, conflict-free.
#pragma unroll 2
    for (int j = 0; j < clen; j += 2) {
        float4 b0 = sb[j];
        float4 b1 = sb[j + 1];
#pragma unroll
        for (int k = 0; k < PPT; ++k) {
            float u0 = __builtin_fmaf(b0.x, ax[k],
                       __builtin_fmaf(b0.y, ay[k],
                       __builtin_fmaf(b0.z, az[k], b0.w)));
            float u1 = __builtin_fmaf(b1.x, ax[k],
                       __builtin_fmaf(b1.y, ay[k],
                       __builtin_fmaf(b1.z, az[k], b1.w)));
            mn[k] = fminf(mn[k], fminf(u0, u1));
        }
    }

    // Plain (coalesced) store of this chunk's partial min
    float* prow = pbase + (size_t)blockIdx.y * nOwn + a_start;
#pragma unroll
    for (int k = 0; k < PPT; ++k)
        prow[threadIdx.x + k * BLOCK] = mn[k];
}

// Phase 2: per point, min over nchunk partials + |a|^2; weighted sum;
// one fp32 atomicAdd per block.
__global__ __launch_bounds__(256) void chamfer_finalize_kernel(
    const float* __restrict__ arr1, const float* __restrict__ arr2,
    const float* __restrict__ part, int BN, int BM, int nchunk,
    float* __restrict__ out)
{
    const int total = BN + BM;
    const float wA = 1.0f / (float)BN;
    const float wB = 1.0f / (float)BM;

    float s = 0.0f;
    for (int i = blockIdx.x * 256 + threadIdx.x; i < total; i += 256 * FBLOCKS) {
        const float* arr;
        const float* pb;
        int idx, stride;
        float w;
        if (i < BN) { arr = arr1; pb = part;                        idx = i;      stride = BN; w = wA; }
        else        { arr = arr2; pb = part + (size_t)nchunk * BN;  idx = i - BN; stride = BM; w = wB; }

        float mn = pb[idx];
        for (int c = 1; c < nchunk; ++c)
            mn = fminf(mn, pb[(size_t)c * stride + idx]);

        float x = arr[idx * 3 + 0], y = arr[idx * 3 + 1], z = arr[idx * 3 + 2];
        s += w * (mn + __builtin_fmaf(x, x, __builtin_fmaf(y, y, z * z)));
    }

    // wave64 shuffle reduce, then cross-wave via LDS
#pragma unroll
    for (int off = 32; off > 0; off >>= 1)
        s += __shfl_down(s, off, 64);

    __shared__ float wsum[4];
    int lane = threadIdx.x & 63, wv = threadIdx.x >> 6;
    if (lane == 0) wsum[wv] = s;
    __syncthreads();
    if (threadIdx.x == 0)
        atomicAdd(out, wsum[0] + wsum[1] + wsum[2] + wsum[3]);
}

extern "C" void kernel_launch(void* const* d_in, const int* in_sizes, int n_in,
                              void* d_out, int out_size, void* d_ws, size_t ws_size,
                              hipStream_t stream)
{
    const float* arr1 = (const float*)d_in[0];
    const float* arr2 = (const float*)d_in[1];
    float* out = (float*)d_out;

    const int Bb = 4;
    const int N = in_sizes[0] / (Bb * 3);   // 8192
    const int M = in_sizes[1] / (Bb * 3);   // 8192
    const int BN = Bb * N, BM = Bb * M;

    // Pick nchunk for parallelism (1024 blocks at 32) but stay inside ws_size.
    int nchunk = NCHUNK;
    while (nchunk > 4 && (size_t)(BN + BM) * (size_t)nchunk * sizeof(float) > ws_size)
        nchunk >>= 1;

    float* part = (float*)d_ws;   // [2][nchunk][32768] partial mins

    const int clen = M / nchunk;  // == N / nchunk (both 8192)
    dim3 grid(BN / (BLOCK * PPT), nchunk, 2);   // (16, nchunk, 2)
    chamfer_min_kernel<<<grid, BLOCK, clen * sizeof(float4), stream>>>(
        arr1, arr2, Bb, N, M, nchunk, part, out);

    chamfer_finalize_kernel<<<FBLOCKS, 256, 0, stream>>>(
        arr1, arr2, part, BN, BM, nchunk, out);
}